// Round 12
// baseline (117.834 us; speedup 1.0000x reference)
//
#include <hip/hip_runtime.h>
#include <hip/hip_bf16.h>
#include <hip/hip_fp16.h>

// b=2, n=4096, d=128, K=32, ein=257, hidden=514, cf=16, node_in=144, node_h=256
#define NNODES 8192
#define NPTS   4096
#define KNN    32
#define EH     514
#define EH2    1028
#define CF     16
#define DD     128
#define ABS    544          // ushort row stride for fp16 A/B halves (pad 514->544, zeros)
#define NPAD   1088         // gemm1 N padded to 17*64
#define NKB    17           // K blocks of 32 (544 = 17*32)
#define NDIN_P 160          // node_in 144 padded
#define NDH    256
#define WCAP   160          // per-node knn candidate capacity (E[n]~44, 16 sigma margin)
#define KNNB   (NNODES / 16) // 512 knn blocks (16 nodes/block, 4 per wave)

typedef __attribute__((ext_vector_type(8))) short short8;
typedef __attribute__((ext_vector_type(8))) unsigned short u16x8;
typedef __attribute__((ext_vector_type(8))) _Float16 half8;
typedef __attribute__((ext_vector_type(4))) float f32x4;

__device__ __forceinline__ float gelu_poly(float v) {
    float t = v * v;
    float u = fmaf(t, -0.0664904f, 0.3989423f);
    float phi = fmaf(v, u, 0.5f);
    return v * phi;
}
__device__ __forceinline__ unsigned short bf16rne(float f) {
    unsigned u = __float_as_uint(f);
    u += 0x7fffu + ((u >> 16) & 1u);
    return (unsigned short)(u >> 16);
}
__device__ __forceinline__ unsigned short f16u(float f) {
    return __half_as_ushort(__float2half(f));
}
__device__ __forceinline__ unsigned pack2bf(float lo, float hi) {
    union { __hip_bfloat162 b; unsigned u; } cv;
    cv.b = __float22bfloat162_rn(float2{lo, hi});
    return cv.u;
}

// ---------------- repack + x SoA + AB pad zeroing fused (hbf removed) ----------------
__global__ __launch_bounds__(256) void repack_kernel(
    const float* __restrict__ We1, const float* __restrict__ be1,
    const float* __restrict__ We2,
    const float* __restrict__ Wn1, const float* __restrict__ Wn2,
    const float* __restrict__ x,
    unsigned short* __restrict__ Wcatbf, float* __restrict__ biascat,
    unsigned short* __restrict__ w3h, unsigned short* __restrict__ W2f,
    unsigned short* __restrict__ Wn1bf, unsigned short* __restrict__ Wn2bf,
    float* __restrict__ xsoa, unsigned short* __restrict__ ABh)
{
    int tid = blockIdx.x * 256 + threadIdx.x;   // grid: 1024 blocks -> 262144 threads
    {   // zero A/B half pad cols 514..543 (8192 rows x 30)
        int row = tid >> 5, cc = tid & 31;
        if (cc < 30) {
            int col = 514 + cc;
            ABh[(size_t)row * ABS + col] = 0;
            ABh[(size_t)NNODES * ABS + (size_t)row * ABS + col] = 0;
        }
    }
    if (tid < 2 * NPTS * 3) {  // x -> SoA
        int b = tid / (NPTS * 3), r = tid - b * NPTS * 3;
        int j = r / 3, comp = r - j * 3;
        xsoa[b * 3 * NPTS + comp * NPTS + j] = x[tid];
    }
    if (tid < NPAD * DD) {
        int nn = tid >> 7, kk = tid & 127;
        float v = (nn < EH) ? We1[nn * 257 + kk]
                : (nn < EH2) ? We1[(nn - EH) * 257 + 128 + kk] : 0.0f;
        Wcatbf[tid] = bf16rne(v);
    }
    if (tid < NPAD) biascat[tid] = (tid < EH) ? be1[tid] : 0.0f;
    if (tid < ABS)  w3h[tid] = (tid < EH) ? f16u(We1[tid * 257 + 256]) : 0;
    if (tid < NKB * 64 * 8) {   // We2 -> fp16 B-fragment layout
        int kb = tid >> 9, l = (tid >> 3) & 63, i = tid & 7;
        int k = kb * 32 + ((l >> 4) << 3) + i;
        int c = l & 15;
        W2f[tid] = (k < EH) ? f16u(We2[c * EH + k]) : 0;
    }
    if (tid < NDH * NDIN_P) {
        int r = tid / NDIN_P, c = tid - r * NDIN_P;
        Wn1bf[tid] = bf16rne((c < 144) ? Wn1[r * 144 + c] : 0.0f);
    }
    if (tid < DD * NDH) Wn2bf[tid] = bf16rne(Wn2[tid]);
}

// ---------------- MFMA GEMM (bf16 in): C = act(A@B^T + bias) (+res) ----------------
template <int ACT, int RES, int OUTBF, int MS>
__global__ __launch_bounds__(256) void mgemm_kernel(
    const unsigned short* __restrict__ A, int lda,
    const unsigned short* __restrict__ B, int ldb,
    const float* __restrict__ bias,
    const float* __restrict__ res, int ldr,
    void* __restrict__ Cv, int ldc,
    int Nreal, int ksteps)
{
    int tid = threadIdx.x;
    int wv = tid >> 6, l = tid & 63;
    int bm = blockIdx.x * (MS * 64);
    int bn = blockIdx.y * 64;
    int r = l & 15, ko = (l >> 4) << 3;
    f32x4 acc[MS][4] = {};
    const unsigned short* Ab0 = A + (size_t)(bm + wv * (MS * 16) + r) * lda + ko;
    const unsigned short* Bb0 = B + (size_t)(bn + r) * ldb + ko;
    for (int ks = 0; ks < ksteps; ++ks) {
        int kk = ks << 5;
        short8 av[MS];
#pragma unroll
        for (int m = 0; m < MS; ++m)
            av[m] = *(const short8*)(Ab0 + (size_t)(m * 16) * lda + kk);
        short8 bv[4];
#pragma unroll
        for (int j = 0; j < 4; ++j)
            bv[j] = *(const short8*)(Bb0 + (size_t)(j * 16) * ldb + kk);
#pragma unroll
        for (int m = 0; m < MS; ++m)
#pragma unroll
            for (int j = 0; j < 4; ++j)
                acc[m][j] = __builtin_amdgcn_mfma_f32_16x16x32_bf16(av[m], bv[j], acc[m][j], 0, 0, 0);
    }
#pragma unroll
    for (int m = 0; m < MS; ++m) {
#pragma unroll
        for (int j = 0; j < 4; ++j) {
            int col = bn + j * 16 + (l & 15);
            float bs = (col < Nreal) ? bias[col] : 0.0f;
#pragma unroll
            for (int i = 0; i < 4; ++i) {
                int row = bm + wv * (MS * 16) + m * 16 + ((l >> 4) << 2) + i;
                float v = acc[m][j][i] + bs;
                if (ACT) v = gelu_poly(v);
                if (col < Nreal) {
                    if (RES) v += res[(size_t)row * ldr + col];
                    if (OUTBF) ((unsigned short*)Cv)[(size_t)row * ldc + col] = bf16rne(v);
                    else       ((float*)Cv)[(size_t)row * ldc + col] = v;
                }
            }
        }
    }
}

// ---------------- fused KNN + GEMM1 ----------------
// blockIdx < KNNB: knn, 16 nodes/block, 4 per wave, float4 point loads shared across
// 4 queries (4x L2 traffic cut). Else: gemm1 block (128x64 tile), A converted from f32 h.
__global__ __launch_bounds__(256) void knn_gemm1_kernel(
    const float* __restrict__ xsoa, int* __restrict__ kidx, float* __restrict__ kdist,
    const float* __restrict__ h, const unsigned short* __restrict__ Wcatbf,
    const float* __restrict__ biascat, unsigned short* __restrict__ ABh)
{
    __shared__ unsigned long long L[16][WCAP];   // 20 KB
    __shared__ int nL[16];
    int tid = threadIdx.x;
    if (blockIdx.x < KNNB) {
        int lane = tid & 63, wv = tid >> 6;
        int nbase = (blockIdx.x << 4) + (wv << 2);     // 4 nodes per wave, same batch
        const float* xs = xsoa + (size_t)(nbase >> 12) * 3 * NPTS;
        const float* ys = xs + NPTS;
        const float* zs = ys + NPTS;
        int ib = nbase & 4095;
        float qx[4], qy[4], qz[4];
#pragma unroll
        for (int q = 0; q < 4; ++q) {
            qx[q] = xs[ib + q]; qy[q] = ys[ib + q]; qz[q] = zs[ib + q];
        }
        if (lane < 4) nL[(wv << 2) + lane] = 0;

        // phase 1: per-lane running min for each of 4 queries; point loads shared
        unsigned long long kmin[4] = {~0ull, ~0ull, ~0ull, ~0ull};
#pragma unroll 2
        for (int c = 0; c < 16; ++c) {
            int j0 = (c << 8) + (lane << 2);
            float4 px = *(const float4*)&xs[j0];
            float4 py = *(const float4*)&ys[j0];
            float4 pz = *(const float4*)&zs[j0];
            const float* pxa = (const float*)&px;
            const float* pya = (const float*)&py;
            const float* pza = (const float*)&pz;
#pragma unroll
            for (int p = 0; p < 4; ++p) {
                float X = pxa[p], Y = pya[p], Z = pza[p];
#pragma unroll
                for (int q = 0; q < 4; ++q) {
                    float dx = qx[q] - X, dy = qy[q] - Y, dz = qz[q] - Z;
                    float d = dx * dx + dy * dy + dz * dz;
                    unsigned long long key =
                        ((unsigned long long)__float_as_uint(d) << 32) | (unsigned)(j0 + p);
                    kmin[q] = key < kmin[q] ? key : kmin[q];
                }
            }
        }
        // 4 interleaved bitonic sorts of the 64 lane-minima
#pragma unroll
        for (int k = 2; k <= 64; k <<= 1) {
#pragma unroll
            for (int jj = k >> 1; jj > 0; jj >>= 1) {
                bool tmin = ((lane & jj) == 0) == ((lane & k) == 0);
#pragma unroll
                for (int q = 0; q < 4; ++q) {
                    unsigned long long o = __shfl_xor(kmin[q], jj);
                    kmin[q] = ((o < kmin[q]) == tmin) ? o : kmin[q];
                }
            }
        }
        unsigned long long T[4];
#pragma unroll
        for (int q = 0; q < 4; ++q) T[q] = __shfl(kmin[q], 31);

        // phase 2: recompute, compact keys <= T[q] into wave-private lists
#pragma unroll 2
        for (int c = 0; c < 16; ++c) {
            int j0 = (c << 8) + (lane << 2);
            float4 px = *(const float4*)&xs[j0];
            float4 py = *(const float4*)&ys[j0];
            float4 pz = *(const float4*)&zs[j0];
            const float* pxa = (const float*)&px;
            const float* pya = (const float*)&py;
            const float* pza = (const float*)&pz;
#pragma unroll
            for (int p = 0; p < 4; ++p) {
                float X = pxa[p], Y = pya[p], Z = pza[p];
#pragma unroll
                for (int q = 0; q < 4; ++q) {
                    float dx = qx[q] - X, dy = qy[q] - Y, dz = qz[q] - Z;
                    float d = dx * dx + dy * dy + dz * dz;
                    unsigned long long key =
                        ((unsigned long long)__float_as_uint(d) << 32) | (unsigned)(j0 + p);
                    if (key <= T[q]) {
                        int pos = atomicAdd(&nL[(wv << 2) + q], 1);
                        if (pos < WCAP) L[(wv << 2) + q][pos] = key;
                    }
                }
            }
        }
        // rank select per node (wave-private lists, no barriers)
#pragma unroll
        for (int q = 0; q < 4; ++q) {
            int li = (wv << 2) + q;
            int n = nL[li];
            n = n < WCAP ? n : WCAP;
            for (int t = lane; t < n; t += 64) {
                unsigned long long key = L[li][t];
                int rank = 0;
                for (int u = 0; u < n; ++u) rank += (L[li][u] < key) ? 1 : 0;
                if (rank < KNN) {
                    kidx[(nbase + q) * KNN + rank] = (int)(unsigned)(key & 0xffffffffull);
                    kdist[(nbase + q) * KNN + rank] = __uint_as_float((unsigned)(key >> 32));
                }
            }
        }
    } else {
        // gemm1: AB = h @ Wcat^T + biascat -> split fp16 halves (A from f32 h, on-the-fly bf16)
        int bid = blockIdx.x - KNNB;
        int wv = tid >> 6, l = tid & 63;
        int bm = (bid & 63) * 128;
        int bn = (bid >> 6) * 64;
        int r = l & 15, ko = (l >> 4) << 3;
        f32x4 acc[2][4] = {};
        const float* Ab0 = h + (size_t)(bm + wv * 32 + r) * DD + ko;
        const unsigned short* Bb0 = Wcatbf + (size_t)(bn + r) * DD + ko;
        for (int ks = 0; ks < 4; ++ks) {
            int kk = ks << 5;
            short8 av[2];
#pragma unroll
            for (int m = 0; m < 2; ++m) {
                float4 a0 = *(const float4*)(Ab0 + (size_t)(m * 16) * DD + kk);
                float4 a1 = *(const float4*)(Ab0 + (size_t)(m * 16) * DD + kk + 4);
                union { short8 s; unsigned u[4]; } cv;
                cv.u[0] = pack2bf(a0.x, a0.y);
                cv.u[1] = pack2bf(a0.z, a0.w);
                cv.u[2] = pack2bf(a1.x, a1.y);
                cv.u[3] = pack2bf(a1.z, a1.w);
                av[m] = cv.s;
            }
            short8 bv[4];
#pragma unroll
            for (int j = 0; j < 4; ++j)
                bv[j] = *(const short8*)(Bb0 + (size_t)(j * 16) * DD + kk);
#pragma unroll
            for (int m = 0; m < 2; ++m)
#pragma unroll
                for (int j = 0; j < 4; ++j)
                    acc[m][j] = __builtin_amdgcn_mfma_f32_16x16x32_bf16(av[m], bv[j], acc[m][j], 0, 0, 0);
        }
#pragma unroll
        for (int m = 0; m < 2; ++m) {
#pragma unroll
            for (int j = 0; j < 4; ++j) {
                int col = bn + j * 16 + (l & 15);
                float bs = (col < EH2) ? biascat[col] : 0.0f;
#pragma unroll
                for (int i = 0; i < 4; ++i) {
                    int row = bm + wv * 32 + m * 16 + ((l >> 4) << 2) + i;
                    float v = acc[m][j][i] + bs;
                    if (col < EH) ABh[(size_t)row * ABS + col] = f16u(v);
                    else if (col < EH2) ABh[(size_t)NNODES * ABS + (size_t)row * ABS + (col - EH)] = f16u(v);
                }
            }
        }
    }
}

// ---------------- edge kernel v7: wave-per-(node,tile), full-K, no cross-wave K-reduce ----------------
__global__ __launch_bounds__(256, 4) void edge_kernel(
    const unsigned short* __restrict__ ABh, const unsigned short* __restrict__ w3h,
    const unsigned short* __restrict__ W2f, const float* __restrict__ be2,
    const float* __restrict__ h,
    const int* __restrict__ kidx, const float* __restrict__ kdist,
    unsigned short* __restrict__ nodein)
{
    __shared__ __align__(16) unsigned short sA[2][ABS];   // 2176 B
    __shared__ __align__(16) unsigned short sW[ABS];      // 1088 B
    __shared__ int   kjs[2][KNN];
    __shared__ float kds[2][KNN];
    __shared__ float sP[4][16];

    int blk = blockIdx.x;
    int node0 = blk << 1;
    int bbase = (node0 >> 12) << 12;
    int tid = threadIdx.x;
    int wv = tid >> 6, lane = tid & 63;
    const unsigned short* Bb = ABh + (size_t)NNODES * ABS;

    {
        const unsigned* Wr0 = (const unsigned*)w3h;
        const unsigned* Ar0 = (const unsigned*)(ABh + (size_t)node0 * ABS);
        const unsigned* Ar1 = (const unsigned*)(ABh + (size_t)(node0 + 1) * ABS);
        for (int o = tid; o < 272; o += 256) {
            ((unsigned*)sW)[o] = Wr0[o];
            ((unsigned*)sA[0])[o] = Ar0[o];
            ((unsigned*)sA[1])[o] = Ar1[o];
        }
    }
    if (tid < 64) {
        int nn = tid >> 5, ee = tid & 31;
        kjs[nn][ee] = kidx[(node0 + nn) * KNN + ee];
        kds[nn][ee] = kdist[(node0 + nn) * KNN + ee];
    }
    {   // h -> nodein copy with on-the-fly bf16 convert
        int nn = tid >> 7, c = tid & 127;
        nodein[(size_t)(node0 + nn) * NDIN_P + c] = bf16rne(h[(size_t)(node0 + nn) * DD + c]);
    }
    if (tid < 32) {
        int nn = tid >> 4;
        nodein[(size_t)(node0 + nn) * NDIN_P + 144 + (tid & 15)] = 0;
    }
    __syncthreads();

    int nn = wv >> 1, t = wv & 1;
    int e = t * 16 + (lane & 15);
    int co = (lane >> 4) << 3;
    int jg = bbase + kjs[nn][e];
    float dist = kds[nn][e];
    __half2 d2 = __half2half2(__float2half(dist));
    const __half2 C1 = __half2half2(__float2half(-0.0664904f));
    const __half2 C0 = __half2half2(__float2half(0.3989423f));
    const __half2 H5 = __half2half2(__float2half(0.5f));

    const unsigned short* Bj = Bb + (size_t)jg * ABS + co;

    union H8 { uint4 d; half8 h8; __half2 h2[4]; };

    uint4 Bv[9];
#pragma unroll
    for (int q = 0; q < 9; ++q) Bv[q] = *(const uint4*)(Bj + (q << 5));

    f32x4 acc = {0.0f, 0.0f, 0.0f, 0.0f};
#pragma unroll
    for (int q = 0; q < 17; ++q) {
        H8 Bc; Bc.d = Bv[q % 9];
        if (q + 9 < 17) Bv[q % 9] = *(const uint4*)(Bj + ((q + 9) << 5));
        int off = co + (q << 5);
        H8 Ac, Wc, P;
        Ac.d = *(const uint4*)&sA[nn][off];
        Wc.d = *(const uint4*)&sW[off];
#pragma unroll
        for (int i = 0; i < 4; ++i) {
            __half2 v = __hfma2(Wc.h2[i], d2, __hadd2(Ac.h2[i], Bc.h2[i]));
            __half2 tt = __hmul2(v, v);
            __half2 u = __hfma2(tt, C1, C0);
            __half2 phi = __hfma2(v, u, H5);
            P.h2[i] = __hmul2(v, phi);
        }
        half8 bw = *(const half8*)&W2f[(q * 64 + lane) * 8];
        acc = __builtin_amdgcn_mfma_f32_16x16x32_f16(P.h8, bw, acc, 0, 0, 0);
    }

    float bias = be2[lane & 15];
    float p = 0.0f;
#pragma unroll
    for (int i = 0; i < 4; ++i) p += gelu_poly(acc[i] + bias);
    p += __shfl_xor(p, 16);
    p += __shfl_xor(p, 32);
    if (lane < 16) sP[wv][lane] = p;
    __syncthreads();
    if (tid < 32) {
        int n2 = tid >> 4, c = tid & 15;
        float mi = sP[n2 * 2][c] + sP[n2 * 2 + 1][c];
        nodein[(size_t)(node0 + n2) * NDIN_P + DD + c] = bf16rne(mi);
    }
}

extern "C" void kernel_launch(void* const* d_in, const int* in_sizes, int n_in,
                              void* d_out, int out_size, void* d_ws, size_t ws_size,
                              hipStream_t stream) {
    const float* h   = (const float*)d_in[0];
    const float* x   = (const float*)d_in[1];
    const float* We1 = (const float*)d_in[2];
    const float* be1 = (const float*)d_in[3];
    const float* We2 = (const float*)d_in[4];
    const float* be2 = (const float*)d_in[5];
    const float* Wn1 = (const float*)d_in[6];
    const float* bn1 = (const float*)d_in[7];
    const float* Wn2 = (const float*)d_in[8];
    const float* bn2 = (const float*)d_in[9];
    float* out = (float*)d_out;

    char* ws = (char*)d_ws;
    size_t off = 0;
    auto alloc = [&](size_t bytes) -> void* {
        void* p = ws + off;
        off = (off + bytes + 255) & ~(size_t)255;
        return p;
    };
    unsigned short* Wcatbf = (unsigned short*)alloc((size_t)NPAD * DD * 2);
    float* biascat = (float*)alloc((size_t)NPAD * 4);
    unsigned short* w3h   = (unsigned short*)alloc((size_t)ABS * 2);
    unsigned short* W2f   = (unsigned short*)alloc((size_t)NKB * 64 * 8 * 2);
    unsigned short* Wn1bf = (unsigned short*)alloc((size_t)NDH * NDIN_P * 2);
    unsigned short* Wn2bf = (unsigned short*)alloc((size_t)DD * NDH * 2);
    float* xsoa   = (float*)alloc((size_t)2 * 3 * NPTS * 4);
    unsigned short* ABh   = (unsigned short*)alloc((size_t)2 * NNODES * ABS * 2);
    int*   kidx   = (int*)alloc((size_t)NNODES * KNN * 4);
    float* kdist  = (float*)alloc((size_t)NNODES * KNN * 4);
    unsigned short* nodein = (unsigned short*)alloc((size_t)NNODES * NDIN_P * 2);
    unsigned short* hidbf  = (unsigned short*)alloc((size_t)NNODES * NDH * 2);

    // 1. repack weights + x SoA + AB pad zeroing (fused)
    repack_kernel<<<1024, 256, 0, stream>>>(
        We1, be1, We2, Wn1, Wn2, x, Wcatbf, biascat, w3h, W2f, Wn1bf, Wn2bf, xsoa, ABh);
    // 2. KNN + GEMM1 overlapped (heterogeneous grid)
    knn_gemm1_kernel<<<KNNB + (NNODES / 128) * (NPAD / 64), 256, 0, stream>>>(
        xsoa, kidx, kdist, h, Wcatbf, biascat, ABh);
    // 3. edge MLP + aggregate -> nodein (bf16, stride 160)
    edge_kernel<<<NNODES / 2, 256, 0, stream>>>(ABh, w3h, W2f, be2, h, kidx, kdist, nodein);
    // 4. hid = gelu(nodein @ Wn1^T + bn1) -> bf16
    mgemm_kernel<1, 0, 1, 1><<<dim3(NNODES / 64, NDH / 64), 256, 0, stream>>>(
        nodein, NDIN_P, Wn1bf, NDIN_P, bn1, nullptr, 0, hidbf, NDH, NDH, NDIN_P / 32);
    // 5. out = hid @ Wn2^T + bn2 + h (f32)
    mgemm_kernel<0, 1, 0, 1><<<dim3(NNODES / 64, DD / 64), 256, 0, stream>>>(
        hidbf, NDH, Wn2bf, NDH, bn2, h, DD, out, DD, DD, NDH / 32);
}

// Round 13
// 111.436 us; speedup vs baseline: 1.0574x; 1.0574x over previous
//
#include <hip/hip_runtime.h>
#include <hip/hip_bf16.h>
#include <hip/hip_fp16.h>

// b=2, n=4096, d=128, K=32, ein=257, hidden=514, cf=16, node_in=144, node_h=256
#define NNODES 8192
#define NPTS   4096
#define KNN    32
#define EH     514
#define EH2    1028
#define CF     16
#define DD     128
#define ABS    544          // ushort row stride for fp16 A/B halves (pad 514->544, zeros)
#define NPAD   1088         // gemm1 N padded to 17*64
#define NKB    17           // K blocks of 32 (544 = 17*32)
#define NDIN_P 160          // node_in 144 padded
#define NDH    256
#define WCAP   160          // per-node knn candidate capacity (E[n]~44)

typedef __attribute__((ext_vector_type(8))) short short8;
typedef __attribute__((ext_vector_type(8))) unsigned short u16x8;
typedef __attribute__((ext_vector_type(8))) _Float16 half8;
typedef __attribute__((ext_vector_type(4))) float f32x4;

__device__ __forceinline__ float gelu_poly(float v) {
    float t = v * v;
    float u = fmaf(t, -0.0664904f, 0.3989423f);
    float phi = fmaf(v, u, 0.5f);
    return v * phi;
}
__device__ __forceinline__ unsigned short bf16rne(float f) {
    unsigned u = __float_as_uint(f);
    u += 0x7fffu + ((u >> 16) & 1u);
    return (unsigned short)(u >> 16);
}
__device__ __forceinline__ unsigned short f16u(float f) {
    return __half_as_ushort(__float2half(f));
}
__device__ __forceinline__ unsigned pack2bf(float lo, float hi) {
    union { __hip_bfloat162 b; unsigned u; } cv;
    cv.b = __float22bfloat162_rn(float2{lo, hi});
    return cv.u;
}

// ---------------- repack + x SoA + AB pad zeroing fused ----------------
__global__ __launch_bounds__(256) void repack_kernel(
    const float* __restrict__ We1, const float* __restrict__ be1,
    const float* __restrict__ We2,
    const float* __restrict__ Wn1, const float* __restrict__ Wn2,
    const float* __restrict__ x,
    unsigned short* __restrict__ Wcatbf, float* __restrict__ biascat,
    unsigned short* __restrict__ w3h, unsigned short* __restrict__ W2f,
    unsigned short* __restrict__ Wn1bf, unsigned short* __restrict__ Wn2bf,
    float* __restrict__ xsoa, unsigned short* __restrict__ ABh)
{
    int tid = blockIdx.x * 256 + threadIdx.x;   // grid: 1024 blocks -> 262144 threads
    {   // zero A/B half pad cols 514..543 (8192 rows x 30)
        int row = tid >> 5, cc = tid & 31;
        if (cc < 30) {
            int col = 514 + cc;
            ABh[(size_t)row * ABS + col] = 0;
            ABh[(size_t)NNODES * ABS + (size_t)row * ABS + col] = 0;
        }
    }
    if (tid < 2 * NPTS * 3) {  // x -> SoA
        int b = tid / (NPTS * 3), r = tid - b * NPTS * 3;
        int j = r / 3, comp = r - j * 3;
        xsoa[b * 3 * NPTS + comp * NPTS + j] = x[tid];
    }
    if (tid < NPAD * DD) {
        int nn = tid >> 7, kk = tid & 127;
        float v = (nn < EH) ? We1[nn * 257 + kk]
                : (nn < EH2) ? We1[(nn - EH) * 257 + 128 + kk] : 0.0f;
        Wcatbf[tid] = bf16rne(v);
    }
    if (tid < NPAD) biascat[tid] = (tid < EH) ? be1[tid] : 0.0f;
    if (tid < ABS)  w3h[tid] = (tid < EH) ? f16u(We1[tid * 257 + 256]) : 0;
    if (tid < NKB * 64 * 8) {   // We2 -> fp16 B-fragment layout
        int kb = tid >> 9, l = (tid >> 3) & 63, i = tid & 7;
        int k = kb * 32 + ((l >> 4) << 3) + i;
        int c = l & 15;
        W2f[tid] = (k < EH) ? f16u(We2[c * EH + k]) : 0;
    }
    if (tid < NDH * NDIN_P) {
        int r = tid / NDIN_P, c = tid - r * NDIN_P;
        Wn1bf[tid] = bf16rne((c < 144) ? Wn1[r * 144 + c] : 0.0f);
    }
    if (tid < DD * NDH) Wn2bf[tid] = bf16rne(Wn2[tid]);
}

// ---------------- MFMA GEMM (bf16 in): C = act(A@B^T + bias) (+res) ----------------
template <int ACT, int RES, int OUTBF, int MS>
__global__ __launch_bounds__(256) void mgemm_kernel(
    const unsigned short* __restrict__ A, int lda,
    const unsigned short* __restrict__ B, int ldb,
    const float* __restrict__ bias,
    const float* __restrict__ res, int ldr,
    void* __restrict__ Cv, int ldc,
    int Nreal, int ksteps)
{
    int tid = threadIdx.x;
    int wv = tid >> 6, l = tid & 63;
    int bm = blockIdx.x * (MS * 64);
    int bn = blockIdx.y * 64;
    int r = l & 15, ko = (l >> 4) << 3;
    f32x4 acc[MS][4] = {};
    const unsigned short* Ab0 = A + (size_t)(bm + wv * (MS * 16) + r) * lda + ko;
    const unsigned short* Bb0 = B + (size_t)(bn + r) * ldb + ko;
    for (int ks = 0; ks < ksteps; ++ks) {
        int kk = ks << 5;
        short8 av[MS];
#pragma unroll
        for (int m = 0; m < MS; ++m)
            av[m] = *(const short8*)(Ab0 + (size_t)(m * 16) * lda + kk);
        short8 bv[4];
#pragma unroll
        for (int j = 0; j < 4; ++j)
            bv[j] = *(const short8*)(Bb0 + (size_t)(j * 16) * ldb + kk);
#pragma unroll
        for (int m = 0; m < MS; ++m)
#pragma unroll
            for (int j = 0; j < 4; ++j)
                acc[m][j] = __builtin_amdgcn_mfma_f32_16x16x32_bf16(av[m], bv[j], acc[m][j], 0, 0, 0);
    }
#pragma unroll
    for (int m = 0; m < MS; ++m) {
#pragma unroll
        for (int j = 0; j < 4; ++j) {
            int col = bn + j * 16 + (l & 15);
            float bs = (col < Nreal) ? bias[col] : 0.0f;
#pragma unroll
            for (int i = 0; i < 4; ++i) {
                int row = bm + wv * (MS * 16) + m * 16 + ((l >> 4) << 2) + i;
                float v = acc[m][j][i] + bs;
                if (ACT) v = gelu_poly(v);
                if (col < Nreal) {
                    if (RES) v += res[(size_t)row * ldr + col];
                    if (OUTBF) ((unsigned short*)Cv)[(size_t)row * ldc + col] = bf16rne(v);
                    else       ((float*)Cv)[(size_t)row * ldc + col] = v;
                }
            }
        }
    }
}

// ---------------- KNN: 2 nodes/wave, 8 nodes/block, float4 shared point loads ----------------
__global__ __launch_bounds__(256) void knn_kernel(
    const float* __restrict__ xsoa, int* __restrict__ kidx, float* __restrict__ kdist)
{
    __shared__ unsigned long long L[8][WCAP];   // 10 KB
    __shared__ int nL[8];
    int tid = threadIdx.x;
    int lane = tid & 63, wv = tid >> 6;
    int nbase = (blockIdx.x << 3) + (wv << 1);     // 2 nodes per wave, same batch
    const float* xs = xsoa + (size_t)(nbase >> 12) * 3 * NPTS;
    const float* ys = xs + NPTS;
    const float* zs = ys + NPTS;
    int ib = nbase & 4095;
    float qx[2], qy[2], qz[2];
#pragma unroll
    for (int q = 0; q < 2; ++q) {
        qx[q] = xs[ib + q]; qy[q] = ys[ib + q]; qz[q] = zs[ib + q];
    }
    if (lane < 2) nL[(wv << 1) + lane] = 0;

    // phase 1: per-lane running min for each of 2 queries; point loads shared
    unsigned long long kmin[2] = {~0ull, ~0ull};
#pragma unroll 4
    for (int c = 0; c < 16; ++c) {
        int j0 = (c << 8) + (lane << 2);
        float4 px = *(const float4*)&xs[j0];
        float4 py = *(const float4*)&ys[j0];
        float4 pz = *(const float4*)&zs[j0];
        const float* pxa = (const float*)&px;
        const float* pya = (const float*)&py;
        const float* pza = (const float*)&pz;
#pragma unroll
        for (int p = 0; p < 4; ++p) {
            float X = pxa[p], Y = pya[p], Z = pza[p];
#pragma unroll
            for (int q = 0; q < 2; ++q) {
                float dx = qx[q] - X, dy = qy[q] - Y, dz = qz[q] - Z;
                float d = dx * dx + dy * dy + dz * dz;
                unsigned long long key =
                    ((unsigned long long)__float_as_uint(d) << 32) | (unsigned)(j0 + p);
                kmin[q] = key < kmin[q] ? key : kmin[q];
            }
        }
    }
    // 2 interleaved bitonic sorts of the 64 lane-minima
#pragma unroll
    for (int k = 2; k <= 64; k <<= 1) {
#pragma unroll
        for (int jj = k >> 1; jj > 0; jj >>= 1) {
            bool tmin = ((lane & jj) == 0) == ((lane & k) == 0);
#pragma unroll
            for (int q = 0; q < 2; ++q) {
                unsigned long long o = __shfl_xor(kmin[q], jj);
                kmin[q] = ((o < kmin[q]) == tmin) ? o : kmin[q];
            }
        }
    }
    unsigned long long T[2];
#pragma unroll
    for (int q = 0; q < 2; ++q) T[q] = __shfl(kmin[q], 31);

    // phase 2: recompute, compact keys <= T[q] into wave-private lists
#pragma unroll 4
    for (int c = 0; c < 16; ++c) {
        int j0 = (c << 8) + (lane << 2);
        float4 px = *(const float4*)&xs[j0];
        float4 py = *(const float4*)&ys[j0];
        float4 pz = *(const float4*)&zs[j0];
        const float* pxa = (const float*)&px;
        const float* pya = (const float*)&py;
        const float* pza = (const float*)&pz;
#pragma unroll
        for (int p = 0; p < 4; ++p) {
            float X = pxa[p], Y = pya[p], Z = pza[p];
#pragma unroll
            for (int q = 0; q < 2; ++q) {
                float dx = qx[q] - X, dy = qy[q] - Y, dz = qz[q] - Z;
                float d = dx * dx + dy * dy + dz * dz;
                unsigned long long key =
                    ((unsigned long long)__float_as_uint(d) << 32) | (unsigned)(j0 + p);
                if (key <= T[q]) {
                    int pos = atomicAdd(&nL[(wv << 1) + q], 1);
                    if (pos < WCAP) L[(wv << 1) + q][pos] = key;
                }
            }
        }
    }
    // rank select per node (wave-private lists, no barriers)
#pragma unroll
    for (int q = 0; q < 2; ++q) {
        int li = (wv << 1) + q;
        int n = nL[li];
        n = n < WCAP ? n : WCAP;
        for (int t = lane; t < n; t += 64) {
            unsigned long long key = L[li][t];
            int rank = 0;
            for (int u = 0; u < n; ++u) rank += (L[li][u] < key) ? 1 : 0;
            if (rank < KNN) {
                kidx[(nbase + q) * KNN + rank] = (int)(unsigned)(key & 0xffffffffull);
                kdist[(nbase + q) * KNN + rank] = __uint_as_float((unsigned)(key >> 32));
            }
        }
    }
}

// ---------------- GEMM1 standalone: AB = h @ Wcat^T + biascat -> split fp16 halves ----------------
__global__ __launch_bounds__(256) void gemm1_kernel(
    const float* __restrict__ h, const unsigned short* __restrict__ Wcatbf,
    const float* __restrict__ biascat, unsigned short* __restrict__ ABh)
{
    int tid = threadIdx.x;
    int bid = blockIdx.x;
    int wv = tid >> 6, l = tid & 63;
    int bm = (bid & 63) * 128;
    int bn = (bid >> 6) * 64;
    int r = l & 15, ko = (l >> 4) << 3;
    f32x4 acc[2][4] = {};
    const float* Ab0 = h + (size_t)(bm + wv * 32 + r) * DD + ko;
    const unsigned short* Bb0 = Wcatbf + (size_t)(bn + r) * DD + ko;
    for (int ks = 0; ks < 4; ++ks) {
        int kk = ks << 5;
        short8 av[2];
#pragma unroll
        for (int m = 0; m < 2; ++m) {
            float4 a0 = *(const float4*)(Ab0 + (size_t)(m * 16) * DD + kk);
            float4 a1 = *(const float4*)(Ab0 + (size_t)(m * 16) * DD + kk + 4);
            union { short8 s; unsigned u[4]; } cv;
            cv.u[0] = pack2bf(a0.x, a0.y);
            cv.u[1] = pack2bf(a0.z, a0.w);
            cv.u[2] = pack2bf(a1.x, a1.y);
            cv.u[3] = pack2bf(a1.z, a1.w);
            av[m] = cv.s;
        }
        short8 bv[4];
#pragma unroll
        for (int j = 0; j < 4; ++j)
            bv[j] = *(const short8*)(Bb0 + (size_t)(j * 16) * DD + kk);
#pragma unroll
        for (int m = 0; m < 2; ++m)
#pragma unroll
            for (int j = 0; j < 4; ++j)
                acc[m][j] = __builtin_amdgcn_mfma_f32_16x16x32_bf16(av[m], bv[j], acc[m][j], 0, 0, 0);
    }
#pragma unroll
    for (int m = 0; m < 2; ++m) {
#pragma unroll
        for (int j = 0; j < 4; ++j) {
            int col = bn + j * 16 + (l & 15);
            float bs = (col < EH2) ? biascat[col] : 0.0f;
#pragma unroll
            for (int i = 0; i < 4; ++i) {
                int row = bm + wv * 32 + m * 16 + ((l >> 4) << 2) + i;
                float v = acc[m][j][i] + bs;
                if (col < EH) ABh[(size_t)row * ABS + col] = f16u(v);
                else if (col < EH2) ABh[(size_t)NNODES * ABS + (size_t)row * ABS + (col - EH)] = f16u(v);
            }
        }
    }
}

// ---------------- edge kernel v7: wave-per-(node,tile), full-K, no cross-wave K-reduce ----------------
__global__ __launch_bounds__(256, 4) void edge_kernel(
    const unsigned short* __restrict__ ABh, const unsigned short* __restrict__ w3h,
    const unsigned short* __restrict__ W2f, const float* __restrict__ be2,
    const float* __restrict__ h,
    const int* __restrict__ kidx, const float* __restrict__ kdist,
    unsigned short* __restrict__ nodein)
{
    __shared__ __align__(16) unsigned short sA[2][ABS];   // 2176 B
    __shared__ __align__(16) unsigned short sW[ABS];      // 1088 B
    __shared__ int   kjs[2][KNN];
    __shared__ float kds[2][KNN];
    __shared__ float sP[4][16];

    int blk = blockIdx.x;
    int node0 = blk << 1;
    int bbase = (node0 >> 12) << 12;
    int tid = threadIdx.x;
    int wv = tid >> 6, lane = tid & 63;
    const unsigned short* Bb = ABh + (size_t)NNODES * ABS;

    {
        const unsigned* Wr0 = (const unsigned*)w3h;
        const unsigned* Ar0 = (const unsigned*)(ABh + (size_t)node0 * ABS);
        const unsigned* Ar1 = (const unsigned*)(ABh + (size_t)(node0 + 1) * ABS);
        for (int o = tid; o < 272; o += 256) {
            ((unsigned*)sW)[o] = Wr0[o];
            ((unsigned*)sA[0])[o] = Ar0[o];
            ((unsigned*)sA[1])[o] = Ar1[o];
        }
    }
    if (tid < 64) {
        int nn = tid >> 5, ee = tid & 31;
        kjs[nn][ee] = kidx[(node0 + nn) * KNN + ee];
        kds[nn][ee] = kdist[(node0 + nn) * KNN + ee];
    }
    {   // h -> nodein copy with on-the-fly bf16 convert
        int nn = tid >> 7, c = tid & 127;
        nodein[(size_t)(node0 + nn) * NDIN_P + c] = bf16rne(h[(size_t)(node0 + nn) * DD + c]);
    }
    if (tid < 32) {
        int nn = tid >> 4;
        nodein[(size_t)(node0 + nn) * NDIN_P + 144 + (tid & 15)] = 0;
    }
    __syncthreads();

    int nn = wv >> 1, t = wv & 1;
    int e = t * 16 + (lane & 15);
    int co = (lane >> 4) << 3;
    int jg = bbase + kjs[nn][e];
    float dist = kds[nn][e];
    __half2 d2 = __half2half2(__float2half(dist));
    const __half2 C1 = __half2half2(__float2half(-0.0664904f));
    const __half2 C0 = __half2half2(__float2half(0.3989423f));
    const __half2 H5 = __half2half2(__float2half(0.5f));

    const unsigned short* Bj = Bb + (size_t)jg * ABS + co;

    union H8 { uint4 d; half8 h8; __half2 h2[4]; };

    uint4 Bv[9];
#pragma unroll
    for (int q = 0; q < 9; ++q) Bv[q] = *(const uint4*)(Bj + (q << 5));

    f32x4 acc = {0.0f, 0.0f, 0.0f, 0.0f};
#pragma unroll
    for (int q = 0; q < 17; ++q) {
        H8 Bc; Bc.d = Bv[q % 9];
        if (q + 9 < 17) Bv[q % 9] = *(const uint4*)(Bj + ((q + 9) << 5));
        int off = co + (q << 5);
        H8 Ac, Wc, P;
        Ac.d = *(const uint4*)&sA[nn][off];
        Wc.d = *(const uint4*)&sW[off];
#pragma unroll
        for (int i = 0; i < 4; ++i) {
            __half2 v = __hfma2(Wc.h2[i], d2, __hadd2(Ac.h2[i], Bc.h2[i]));
            __half2 tt = __hmul2(v, v);
            __half2 u = __hfma2(tt, C1, C0);
            __half2 phi = __hfma2(v, u, H5);
            P.h2[i] = __hmul2(v, phi);
        }
        half8 bw = *(const half8*)&W2f[(q * 64 + lane) * 8];
        acc = __builtin_amdgcn_mfma_f32_16x16x32_f16(P.h8, bw, acc, 0, 0, 0);
    }

    float bias = be2[lane & 15];
    float p = 0.0f;
#pragma unroll
    for (int i = 0; i < 4; ++i) p += gelu_poly(acc[i] + bias);
    p += __shfl_xor(p, 16);
    p += __shfl_xor(p, 32);
    if (lane < 16) sP[wv][lane] = p;
    __syncthreads();
    if (tid < 32) {
        int n2 = tid >> 4, c = tid & 15;
        float mi = sP[n2 * 2][c] + sP[n2 * 2 + 1][c];
        nodein[(size_t)(node0 + n2) * NDIN_P + DD + c] = bf16rne(mi);
    }
}

extern "C" void kernel_launch(void* const* d_in, const int* in_sizes, int n_in,
                              void* d_out, int out_size, void* d_ws, size_t ws_size,
                              hipStream_t stream) {
    const float* h   = (const float*)d_in[0];
    const float* x   = (const float*)d_in[1];
    const float* We1 = (const float*)d_in[2];
    const float* be1 = (const float*)d_in[3];
    const float* We2 = (const float*)d_in[4];
    const float* be2 = (const float*)d_in[5];
    const float* Wn1 = (const float*)d_in[6];
    const float* bn1 = (const float*)d_in[7];
    const float* Wn2 = (const float*)d_in[8];
    const float* bn2 = (const float*)d_in[9];
    float* out = (float*)d_out;

    char* ws = (char*)d_ws;
    size_t off = 0;
    auto alloc = [&](size_t bytes) -> void* {
        void* p = ws + off;
        off = (off + bytes + 255) & ~(size_t)255;
        return p;
    };
    unsigned short* Wcatbf = (unsigned short*)alloc((size_t)NPAD * DD * 2);
    float* biascat = (float*)alloc((size_t)NPAD * 4);
    unsigned short* w3h   = (unsigned short*)alloc((size_t)ABS * 2);
    unsigned short* W2f   = (unsigned short*)alloc((size_t)NKB * 64 * 8 * 2);
    unsigned short* Wn1bf = (unsigned short*)alloc((size_t)NDH * NDIN_P * 2);
    unsigned short* Wn2bf = (unsigned short*)alloc((size_t)DD * NDH * 2);
    float* xsoa   = (float*)alloc((size_t)2 * 3 * NPTS * 4);
    unsigned short* ABh   = (unsigned short*)alloc((size_t)2 * NNODES * ABS * 2);
    int*   kidx   = (int*)alloc((size_t)NNODES * KNN * 4);
    float* kdist  = (float*)alloc((size_t)NNODES * KNN * 4);
    unsigned short* nodein = (unsigned short*)alloc((size_t)NNODES * NDIN_P * 2);
    unsigned short* hidbf  = (unsigned short*)alloc((size_t)NNODES * NDH * 2);

    // 1. repack weights + x SoA + AB pad zeroing (fused)
    repack_kernel<<<1024, 256, 0, stream>>>(
        We1, be1, We2, Wn1, Wn2, x, Wcatbf, biascat, w3h, W2f, Wn1bf, Wn2bf, xsoa, ABh);
    // 2. KNN (2 nodes/wave, 8 per block)
    knn_kernel<<<NNODES / 8, 256, 0, stream>>>(xsoa, kidx, kdist);
    // 3. GEMM1 (standalone)
    gemm1_kernel<<<(NNODES / 128) * (NPAD / 64), 256, 0, stream>>>(h, Wcatbf, biascat, ABh);
    // 4. edge MLP + aggregate -> nodein (bf16, stride 160)
    edge_kernel<<<NNODES / 2, 256, 0, stream>>>(ABh, w3h, W2f, be2, h, kidx, kdist, nodein);
    // 5. hid = gelu(nodein @ Wn1^T + bn1) -> bf16
    mgemm_kernel<1, 0, 1, 1><<<dim3(NNODES / 64, NDH / 64), 256, 0, stream>>>(
        nodein, NDIN_P, Wn1bf, NDIN_P, bn1, nullptr, 0, hidbf, NDH, NDH, NDIN_P / 32);
    // 6. out = hid @ Wn2^T + bn2 + h (f32)
    mgemm_kernel<0, 1, 0, 1><<<dim3(NNODES / 64, DD / 64), 256, 0, stream>>>(
        hidbf, NDH, Wn2bf, NDH, bn2, h, DD, out, DD, DD, NDH / 32);
}

// Round 14
// 106.760 us; speedup vs baseline: 1.1037x; 1.0438x over previous
//
#include <hip/hip_runtime.h>
#include <hip/hip_bf16.h>
#include <hip/hip_fp16.h>

// b=2, n=4096, d=128, K=32, ein=257, hidden=514, cf=16, node_in=144, node_h=256
#define NNODES 8192
#define NPTS   4096
#define KNN    32
#define EH     514
#define EH2    1028
#define CF     16
#define DD     128
#define ABS    544          // ushort row stride for fp16 A/B halves (pad 514->544, zeros)
#define NPAD   1088         // gemm1 N padded to 17*64
#define NKB    17           // K blocks of 32 (544 = 17*32)
#define NDIN_P 160          // node_in 144 padded
#define NDH    256
#define WCAP   160          // per-node knn candidate capacity (E[n]~44)
#define HS     264          // shid LDS row stride (ushorts): 528B = 33*16, 16B-aligned

typedef __attribute__((ext_vector_type(8))) short short8;
typedef __attribute__((ext_vector_type(8))) unsigned short u16x8;
typedef __attribute__((ext_vector_type(8))) _Float16 half8;
typedef __attribute__((ext_vector_type(4))) float f32x4;

__device__ __forceinline__ float gelu_poly(float v) {
    float t = v * v;
    float u = fmaf(t, -0.0664904f, 0.3989423f);
    float phi = fmaf(v, u, 0.5f);
    return v * phi;
}
__device__ __forceinline__ unsigned short bf16rne(float f) {
    unsigned u = __float_as_uint(f);
    u += 0x7fffu + ((u >> 16) & 1u);
    return (unsigned short)(u >> 16);
}
__device__ __forceinline__ unsigned short f16u(float f) {
    return __half_as_ushort(__float2half(f));
}
__device__ __forceinline__ unsigned pack2bf(float lo, float hi) {
    union { __hip_bfloat162 b; unsigned u; } cv;
    cv.b = __float22bfloat162_rn(float2{lo, hi});
    return cv.u;
}

// ---------------- repack + x SoA (pad zeroing moved to gemm1) ----------------
__global__ __launch_bounds__(256) void repack_kernel(
    const float* __restrict__ We1, const float* __restrict__ be1,
    const float* __restrict__ We2,
    const float* __restrict__ Wn1, const float* __restrict__ Wn2,
    const float* __restrict__ x,
    unsigned short* __restrict__ Wcatbf, float* __restrict__ biascat,
    unsigned short* __restrict__ w3h, unsigned short* __restrict__ W2f,
    unsigned short* __restrict__ Wn1bf, unsigned short* __restrict__ Wn2bf,
    float* __restrict__ xsoa)
{
    int tid = blockIdx.x * 256 + threadIdx.x;   // grid: 544 blocks -> 139264 threads
    if (tid < 2 * NPTS * 3) {  // x -> SoA
        int b = tid / (NPTS * 3), r = tid - b * NPTS * 3;
        int j = r / 3, comp = r - j * 3;
        xsoa[b * 3 * NPTS + comp * NPTS + j] = x[tid];
    }
    if (tid < NPAD * DD) {
        int nn = tid >> 7, kk = tid & 127;
        float v = (nn < EH) ? We1[nn * 257 + kk]
                : (nn < EH2) ? We1[(nn - EH) * 257 + 128 + kk] : 0.0f;
        Wcatbf[tid] = bf16rne(v);
    }
    if (tid < NPAD) biascat[tid] = (tid < EH) ? be1[tid] : 0.0f;
    if (tid < ABS)  w3h[tid] = (tid < EH) ? f16u(We1[tid * 257 + 256]) : 0;
    if (tid < NKB * 64 * 8) {   // We2 -> fp16 B-fragment layout
        int kb = tid >> 9, l = (tid >> 3) & 63, i = tid & 7;
        int k = kb * 32 + ((l >> 4) << 3) + i;
        int c = l & 15;
        W2f[tid] = (k < EH) ? f16u(We2[c * EH + k]) : 0;
    }
    if (tid < NDH * NDIN_P) {
        int r = tid / NDIN_P, c = tid - r * NDIN_P;
        Wn1bf[tid] = bf16rne((c < 144) ? Wn1[r * 144 + c] : 0.0f);
    }
    if (tid < DD * NDH) Wn2bf[tid] = bf16rne(Wn2[tid]);
}

// ---------------- KNN: 2 nodes/wave, 8 nodes/block, float4 shared point loads ----------------
__global__ __launch_bounds__(256) void knn_kernel(
    const float* __restrict__ xsoa, int* __restrict__ kidx, float* __restrict__ kdist)
{
    __shared__ unsigned long long L[8][WCAP];   // 10 KB
    __shared__ int nL[8];
    int tid = threadIdx.x;
    int lane = tid & 63, wv = tid >> 6;
    int nbase = (blockIdx.x << 3) + (wv << 1);     // 2 nodes per wave, same batch
    const float* xs = xsoa + (size_t)(nbase >> 12) * 3 * NPTS;
    const float* ys = xs + NPTS;
    const float* zs = ys + NPTS;
    int ib = nbase & 4095;
    float qx[2], qy[2], qz[2];
#pragma unroll
    for (int q = 0; q < 2; ++q) {
        qx[q] = xs[ib + q]; qy[q] = ys[ib + q]; qz[q] = zs[ib + q];
    }
    if (lane < 2) nL[(wv << 1) + lane] = 0;

    unsigned long long kmin[2] = {~0ull, ~0ull};
#pragma unroll 4
    for (int c = 0; c < 16; ++c) {
        int j0 = (c << 8) + (lane << 2);
        float4 px = *(const float4*)&xs[j0];
        float4 py = *(const float4*)&ys[j0];
        float4 pz = *(const float4*)&zs[j0];
        const float* pxa = (const float*)&px;
        const float* pya = (const float*)&py;
        const float* pza = (const float*)&pz;
#pragma unroll
        for (int p = 0; p < 4; ++p) {
            float X = pxa[p], Y = pya[p], Z = pza[p];
#pragma unroll
            for (int q = 0; q < 2; ++q) {
                float dx = qx[q] - X, dy = qy[q] - Y, dz = qz[q] - Z;
                float d = dx * dx + dy * dy + dz * dz;
                unsigned long long key =
                    ((unsigned long long)__float_as_uint(d) << 32) | (unsigned)(j0 + p);
                kmin[q] = key < kmin[q] ? key : kmin[q];
            }
        }
    }
#pragma unroll
    for (int k = 2; k <= 64; k <<= 1) {
#pragma unroll
        for (int jj = k >> 1; jj > 0; jj >>= 1) {
            bool tmin = ((lane & jj) == 0) == ((lane & k) == 0);
#pragma unroll
            for (int q = 0; q < 2; ++q) {
                unsigned long long o = __shfl_xor(kmin[q], jj);
                kmin[q] = ((o < kmin[q]) == tmin) ? o : kmin[q];
            }
        }
    }
    unsigned long long T[2];
#pragma unroll
    for (int q = 0; q < 2; ++q) T[q] = __shfl(kmin[q], 31);

#pragma unroll 4
    for (int c = 0; c < 16; ++c) {
        int j0 = (c << 8) + (lane << 2);
        float4 px = *(const float4*)&xs[j0];
        float4 py = *(const float4*)&ys[j0];
        float4 pz = *(const float4*)&zs[j0];
        const float* pxa = (const float*)&px;
        const float* pya = (const float*)&py;
        const float* pza = (const float*)&pz;
#pragma unroll
        for (int p = 0; p < 4; ++p) {
            float X = pxa[p], Y = pya[p], Z = pza[p];
#pragma unroll
            for (int q = 0; q < 2; ++q) {
                float dx = qx[q] - X, dy = qy[q] - Y, dz = qz[q] - Z;
                float d = dx * dx + dy * dy + dz * dz;
                unsigned long long key =
                    ((unsigned long long)__float_as_uint(d) << 32) | (unsigned)(j0 + p);
                if (key <= T[q]) {
                    int pos = atomicAdd(&nL[(wv << 1) + q], 1);
                    if (pos < WCAP) L[(wv << 1) + q][pos] = key;
                }
            }
        }
    }
#pragma unroll
    for (int q = 0; q < 2; ++q) {
        int li = (wv << 1) + q;
        int n = nL[li];
        n = n < WCAP ? n : WCAP;
        for (int t = lane; t < n; t += 64) {
            unsigned long long key = L[li][t];
            int rank = 0;
            for (int u = 0; u < n; ++u) rank += (L[li][u] < key) ? 1 : 0;
            if (rank < KNN) {
                kidx[(nbase + q) * KNN + rank] = (int)(unsigned)(key & 0xffffffffull);
                kdist[(nbase + q) * KNN + rank] = __uint_as_float((unsigned)(key >> 32));
            }
        }
    }
}

// ---------------- GEMM1: AB = h @ Wcat^T + biascat -> split fp16 halves + pad writes ----------------
// Virtual cols 1028..1087 compute exact 0 (zero Wcat rows, zero bias) and are remapped
// onto A/B pad cols 514..543 -- replaces repack's scattered pad-zero stores.
__global__ __launch_bounds__(256) void gemm1_kernel(
    const float* __restrict__ h, const unsigned short* __restrict__ Wcatbf,
    const float* __restrict__ biascat, unsigned short* __restrict__ ABh)
{
    int tid = threadIdx.x;
    int bid = blockIdx.x;
    int wv = tid >> 6, l = tid & 63;
    int bm = (bid & 63) * 128;
    int bn = (bid >> 6) * 64;
    int r = l & 15, ko = (l >> 4) << 3;
    f32x4 acc[2][4] = {};
    const float* Ab0 = h + (size_t)(bm + wv * 32 + r) * DD + ko;
    const unsigned short* Bb0 = Wcatbf + (size_t)(bn + r) * DD + ko;
    for (int ks = 0; ks < 4; ++ks) {
        int kk = ks << 5;
        short8 av[2];
#pragma unroll
        for (int m = 0; m < 2; ++m) {
            float4 a0 = *(const float4*)(Ab0 + (size_t)(m * 16) * DD + kk);
            float4 a1 = *(const float4*)(Ab0 + (size_t)(m * 16) * DD + kk + 4);
            union { short8 s; unsigned u[4]; } cv;
            cv.u[0] = pack2bf(a0.x, a0.y);
            cv.u[1] = pack2bf(a0.z, a0.w);
            cv.u[2] = pack2bf(a1.x, a1.y);
            cv.u[3] = pack2bf(a1.z, a1.w);
            av[m] = cv.s;
        }
        short8 bv[4];
#pragma unroll
        for (int j = 0; j < 4; ++j)
            bv[j] = *(const short8*)(Bb0 + (size_t)(j * 16) * DD + kk);
#pragma unroll
        for (int m = 0; m < 2; ++m)
#pragma unroll
            for (int j = 0; j < 4; ++j)
                acc[m][j] = __builtin_amdgcn_mfma_f32_16x16x32_bf16(av[m], bv[j], acc[m][j], 0, 0, 0);
    }
#pragma unroll
    for (int m = 0; m < 2; ++m) {
#pragma unroll
        for (int j = 0; j < 4; ++j) {
            int col = bn + j * 16 + (l & 15);
            float bs = (col < EH2) ? biascat[col] : 0.0f;
#pragma unroll
            for (int i = 0; i < 4; ++i) {
                int row = bm + wv * 32 + m * 16 + ((l >> 4) << 2) + i;
                float v = acc[m][j][i] + bs;
                unsigned short hv = f16u(v);
                if (col < EH)        ABh[(size_t)row * ABS + col] = hv;
                else if (col < EH2)  ABh[(size_t)NNODES * ABS + (size_t)row * ABS + (col - EH)] = hv;
                else if (col < 1058) ABh[(size_t)row * ABS + (col - 514)] = hv;                          // A pad (=0)
                else                 ABh[(size_t)NNODES * ABS + (size_t)row * ABS + (col - 544)] = hv;   // B pad (=0)
            }
        }
    }
}

// ---------------- edge kernel: wave-per-(node,tile), full-K, no cross-wave K-reduce ----------------
__global__ __launch_bounds__(256, 4) void edge_kernel(
    const unsigned short* __restrict__ ABh, const unsigned short* __restrict__ w3h,
    const unsigned short* __restrict__ W2f, const float* __restrict__ be2,
    const float* __restrict__ h,
    const int* __restrict__ kidx, const float* __restrict__ kdist,
    unsigned short* __restrict__ nodein)
{
    __shared__ __align__(16) unsigned short sA[2][ABS];   // 2176 B
    __shared__ __align__(16) unsigned short sW[ABS];      // 1088 B
    __shared__ int   kjs[2][KNN];
    __shared__ float kds[2][KNN];
    __shared__ float sP[4][16];

    int blk = blockIdx.x;
    int node0 = blk << 1;
    int bbase = (node0 >> 12) << 12;
    int tid = threadIdx.x;
    int wv = tid >> 6, lane = tid & 63;
    const unsigned short* Bb = ABh + (size_t)NNODES * ABS;

    {
        const unsigned* Wr0 = (const unsigned*)w3h;
        const unsigned* Ar0 = (const unsigned*)(ABh + (size_t)node0 * ABS);
        const unsigned* Ar1 = (const unsigned*)(ABh + (size_t)(node0 + 1) * ABS);
        for (int o = tid; o < 272; o += 256) {
            ((unsigned*)sW)[o] = Wr0[o];
            ((unsigned*)sA[0])[o] = Ar0[o];
            ((unsigned*)sA[1])[o] = Ar1[o];
        }
    }
    if (tid < 64) {
        int nn = tid >> 5, ee = tid & 31;
        kjs[nn][ee] = kidx[(node0 + nn) * KNN + ee];
        kds[nn][ee] = kdist[(node0 + nn) * KNN + ee];
    }
    {   // h -> nodein copy with on-the-fly bf16 convert
        int nn = tid >> 7, c = tid & 127;
        nodein[(size_t)(node0 + nn) * NDIN_P + c] = bf16rne(h[(size_t)(node0 + nn) * DD + c]);
    }
    if (tid < 32) {
        int nn = tid >> 4;
        nodein[(size_t)(node0 + nn) * NDIN_P + 144 + (tid & 15)] = 0;
    }
    __syncthreads();

    int nn = wv >> 1, t = wv & 1;
    int e = t * 16 + (lane & 15);
    int co = (lane >> 4) << 3;
    int jg = bbase + kjs[nn][e];
    float dist = kds[nn][e];
    __half2 d2 = __half2half2(__float2half(dist));
    const __half2 C1 = __half2half2(__float2half(-0.0664904f));
    const __half2 C0 = __half2half2(__float2half(0.3989423f));
    const __half2 H5 = __half2half2(__float2half(0.5f));

    const unsigned short* Bj = Bb + (size_t)jg * ABS + co;

    union H8 { uint4 d; half8 h8; __half2 h2[4]; };

    uint4 Bv[9];
#pragma unroll
    for (int q = 0; q < 9; ++q) Bv[q] = *(const uint4*)(Bj + (q << 5));

    f32x4 acc = {0.0f, 0.0f, 0.0f, 0.0f};
#pragma unroll
    for (int q = 0; q < 17; ++q) {
        H8 Bc; Bc.d = Bv[q % 9];
        if (q + 9 < 17) Bv[q % 9] = *(const uint4*)(Bj + ((q + 9) << 5));
        int off = co + (q << 5);
        H8 Ac, Wc, P;
        Ac.d = *(const uint4*)&sA[nn][off];
        Wc.d = *(const uint4*)&sW[off];
#pragma unroll
        for (int i = 0; i < 4; ++i) {
            __half2 v = __hfma2(Wc.h2[i], d2, __hadd2(Ac.h2[i], Bc.h2[i]));
            __half2 tt = __hmul2(v, v);
            __half2 u = __hfma2(tt, C1, C0);
            __half2 phi = __hfma2(v, u, H5);
            P.h2[i] = __hmul2(v, phi);
        }
        half8 bw = *(const half8*)&W2f[(q * 64 + lane) * 8];
        acc = __builtin_amdgcn_mfma_f32_16x16x32_f16(P.h8, bw, acc, 0, 0, 0);
    }

    float bias = be2[lane & 15];
    float p = 0.0f;
#pragma unroll
    for (int i = 0; i < 4; ++i) p += gelu_poly(acc[i] + bias);
    p += __shfl_xor(p, 16);
    p += __shfl_xor(p, 32);
    if (lane < 16) sP[wv][lane] = p;
    __syncthreads();
    if (tid < 32) {
        int n2 = tid >> 4, c = tid & 15;
        float mi = sP[n2 * 2][c] + sP[n2 * 2 + 1][c];
        nodein[(size_t)(node0 + n2) * NDIN_P + DD + c] = bf16rne(mi);
    }
}

// ---------------- fused node MLP: hid = gelu(nodein@Wn1^T+bn1); out = hid@Wn2^T+bn2+h ----------------
// 32 rows/block (256 blocks). hid tile parked in LDS between the two MFMA passes.
__global__ __launch_bounds__(256) void gemm23_kernel(
    const unsigned short* __restrict__ nodein,
    const unsigned short* __restrict__ Wn1bf, const float* __restrict__ bn1,
    const unsigned short* __restrict__ Wn2bf, const float* __restrict__ bn2,
    const float* __restrict__ h, float* __restrict__ out)
{
    __shared__ __align__(16) unsigned short shid[32][HS];   // 16.5 KB

    int tid = threadIdx.x;
    int wv = tid >> 6, l = tid & 63;
    int bm = blockIdx.x * 32;
    int r = l & 15, ko = (l >> 4) << 3;

    // --- pass 1: hid[32][wv*64 .. +64] = gelu(nodein @ Wn1^T + bn1) ---
    {
        f32x4 acc[2][4] = {};
        const unsigned short* Ab0 = nodein + (size_t)(bm + r) * NDIN_P + ko;
        const unsigned short* Bb0 = Wn1bf + (size_t)(wv * 64 + r) * NDIN_P + ko;
        for (int ks = 0; ks < 5; ++ks) {
            int kk = ks << 5;
            short8 av[2];
#pragma unroll
            for (int m = 0; m < 2; ++m)
                av[m] = *(const short8*)(Ab0 + (size_t)(m * 16) * NDIN_P + kk);
            short8 bv[4];
#pragma unroll
            for (int j = 0; j < 4; ++j)
                bv[j] = *(const short8*)(Bb0 + (size_t)(j * 16) * NDIN_P + kk);
#pragma unroll
            for (int m = 0; m < 2; ++m)
#pragma unroll
                for (int j = 0; j < 4; ++j)
                    acc[m][j] = __builtin_amdgcn_mfma_f32_16x16x32_bf16(av[m], bv[j], acc[m][j], 0, 0, 0);
        }
#pragma unroll
        for (int m = 0; m < 2; ++m) {
#pragma unroll
            for (int j = 0; j < 4; ++j) {
                int col = wv * 64 + j * 16 + (l & 15);
                float bs = bn1[col];
#pragma unroll
                for (int i = 0; i < 4; ++i) {
                    int row = m * 16 + ((l >> 4) << 2) + i;
                    shid[row][col] = bf16rne(gelu_poly(acc[m][j][i] + bs));
                }
            }
        }
    }
    __syncthreads();

    // --- pass 2: out[32][wv*32 .. +32] = shid @ Wn2^T + bn2 + h ---
    {
        f32x4 acc[2][2] = {};
        const unsigned short* Bb0 = Wn2bf + (size_t)(wv * 32 + r) * NDH + ko;
        for (int ks = 0; ks < 8; ++ks) {
            int kk = ks << 5;
            short8 av[2];
#pragma unroll
            for (int m = 0; m < 2; ++m)
                av[m] = *(const short8*)&shid[m * 16 + r][kk + ko];
            short8 bv[2];
#pragma unroll
            for (int j = 0; j < 2; ++j)
                bv[j] = *(const short8*)(Bb0 + (size_t)(j * 16) * NDH + kk);
#pragma unroll
            for (int m = 0; m < 2; ++m)
#pragma unroll
                for (int j = 0; j < 2; ++j)
                    acc[m][j] = __builtin_amdgcn_mfma_f32_16x16x32_bf16(av[m], bv[j], acc[m][j], 0, 0, 0);
        }
#pragma unroll
        for (int m = 0; m < 2; ++m) {
#pragma unroll
            for (int j = 0; j < 2; ++j) {
                int col = wv * 32 + j * 16 + (l & 15);
                float bs = bn2[col];
#pragma unroll
                for (int i = 0; i < 4; ++i) {
                    int row = bm + m * 16 + ((l >> 4) << 2) + i;
                    out[(size_t)row * DD + col] = acc[m][j][i] + bs + h[(size_t)row * DD + col];
                }
            }
        }
    }
}

extern "C" void kernel_launch(void* const* d_in, const int* in_sizes, int n_in,
                              void* d_out, int out_size, void* d_ws, size_t ws_size,
                              hipStream_t stream) {
    const float* h   = (const float*)d_in[0];
    const float* x   = (const float*)d_in[1];
    const float* We1 = (const float*)d_in[2];
    const float* be1 = (const float*)d_in[3];
    const float* We2 = (const float*)d_in[4];
    const float* be2 = (const float*)d_in[5];
    const float* Wn1 = (const float*)d_in[6];
    const float* bn1 = (const float*)d_in[7];
    const float* Wn2 = (const float*)d_in[8];
    const float* bn2 = (const float*)d_in[9];
    float* out = (float*)d_out;

    char* ws = (char*)d_ws;
    size_t off = 0;
    auto alloc = [&](size_t bytes) -> void* {
        void* p = ws + off;
        off = (off + bytes + 255) & ~(size_t)255;
        return p;
    };
    unsigned short* Wcatbf = (unsigned short*)alloc((size_t)NPAD * DD * 2);
    float* biascat = (float*)alloc((size_t)NPAD * 4);
    unsigned short* w3h   = (unsigned short*)alloc((size_t)ABS * 2);
    unsigned short* W2f   = (unsigned short*)alloc((size_t)NKB * 64 * 8 * 2);
    unsigned short* Wn1bf = (unsigned short*)alloc((size_t)NDH * NDIN_P * 2);
    unsigned short* Wn2bf = (unsigned short*)alloc((size_t)DD * NDH * 2);
    float* xsoa   = (float*)alloc((size_t)2 * 3 * NPTS * 4);
    unsigned short* ABh   = (unsigned short*)alloc((size_t)2 * NNODES * ABS * 2);
    int*   kidx   = (int*)alloc((size_t)NNODES * KNN * 4);
    float* kdist  = (float*)alloc((size_t)NNODES * KNN * 4);
    unsigned short* nodein = (unsigned short*)alloc((size_t)NNODES * NDIN_P * 2);

    // 1. repack weights + x SoA
    repack_kernel<<<544, 256, 0, stream>>>(
        We1, be1, We2, Wn1, Wn2, x, Wcatbf, biascat, w3h, W2f, Wn1bf, Wn2bf, xsoa);
    // 2. KNN (2 nodes/wave, 8 per block)
    knn_kernel<<<NNODES / 8, 256, 0, stream>>>(xsoa, kidx, kdist);
    // 3. GEMM1 (+ pad writes via dead columns)
    gemm1_kernel<<<(NNODES / 128) * (NPAD / 64), 256, 0, stream>>>(h, Wcatbf, biascat, ABh);
    // 4. edge MLP + aggregate -> nodein (bf16, stride 160)
    edge_kernel<<<NNODES / 2, 256, 0, stream>>>(ABh, w3h, W2f, be2, h, kidx, kdist, nodein);
    // 5. fused node MLP: hid in LDS, out = ... + h
    gemm23_kernel<<<NNODES / 32, 256, 0, stream>>>(nodein, Wn1bf, bn1, Wn2bf, bn2, h, out);
}